// Round 6
// baseline (270.692 us; speedup 1.0000x reference)
//
#include <hip/hip_runtime.h>
#include <hip/hip_bf16.h>

#define BB   4
#define LL   8192
#define HH   256
#define NN   64
#define NSEG 128
#define LSEG 64

// ws layout (bytes):
//       0 : lam[2*NN]    f32 (512)     lambda (re,im)
//     512 : lam64[2*NN]  f32 (512)     lambda^64
//    1024 : flags[8]     i32 (32)
//    1088 : Df[HH]       f32 (1024)
//    2112 : CBt[128*HH]  f32 (131072)  [n2][h]
//  133184 : Ktab[64*HH]  f32 (65536)   [j][h]  conv taps K[h,j]=Re(sum_n CB lam^j)
//  198720 : Vre[64*64]   f32 (16384)   [n][tau] Re(lam_n^{tau+1})
//  215104 : Vim[64*64]   f32 (16384)   [n][tau] Im(lam_n^{tau+1})
//  262144 : Abuf         bf16(33554432)[bg][s][n][reim][64 h]  A -> (scan) -> U
//
// DTYPE MODEL (validated R0-R3): output fp32; inputs mixed, via k_sniff.
// R6: Toeplitz decomposition. y[64s+16u+t] = D*x + conv(K[h,0..16u+t], x local)
//     + sum_n2 U[s][n2]*V[n2][16u+t],  U[s] = CB*S_{s-1} (scan epilogue,
//     in-place over Abuf). k_out: 8192 waves, 16 outputs each, ~2.7k FMA/lane
//     vs 24.5k VALU/lane in the state-recurrence form.

__device__ __forceinline__ float ldF(const void* p, size_t i, int isbf) {
    return isbf ? __bfloat162float(((const __hip_bfloat16*)p)[i])
                : ((const float*)p)[i];
}

__global__ void k_sniff(const void* p0, const void* p1, const void* p2,
                        const void* p3, const void* p4, const void* p5,
                        const void* p6, const void* p7, int* flags)
{
    int t = threadIdx.x;
    if (t < 8) {
        const void* ps[8] = {p0, p1, p2, p3, p4, p5, p6, p7};
        const unsigned int* d = (const unsigned int*)ps[t];
        int nbf = 0, nrand = 0;
        for (int i = 0; i < 32; ++i) {
            unsigned int lo = d[i] & 0xFFFFu;
            unsigned int e  = (lo >> 7) & 0xFFu;
            if (lo == 0u) { /* neutral */ }
            else if (e >= 90u && e <= 140u) nbf++;
            else nrand++;
        }
        flags[t] = (nrand == 0 && nbf >= 8) ? 1 : 0;
    }
}

__global__ __launch_bounds__(256) void k_setup(
    const void* nu_log, const void* theta_log,
    const void* B_re, const void* B_im,
    const void* C_re, const void* C_im,
    const void* D, const int* __restrict__ flags,
    float* lam, float* lam64, float* Df, float* CBt,
    float* Vre, float* Vim)
{
    int t = blockIdx.x * 256 + threadIdx.x;
    if (t < NN) {
        float nu = expf(ldF(nu_log, t, flags[1]));
        float th = expf(ldF(theta_log, t, flags[2]));
        float a  = expf(-nu);
        lam[2*t]   = a * cosf(th);
        lam[2*t+1] = a * sinf(th);
        float a64 = expf(-64.0f * nu);
        float ph  = 64.0f * th;
        lam64[2*t]   = a64 * cosf(ph);
        lam64[2*t+1] = a64 * sinf(ph);
    }
    if (t < HH) Df[t] = ldF(D, t, flags[7]);
    if (t < HH * NN) {
        int h = t >> 6, n = t & 63;
        float bre = ldF(B_re, h*NN+n, flags[3]);
        float bim = ldF(B_im, h*NN+n, flags[4]);
        float cre = ldF(C_re, h*NN+n, flags[5]);
        float cim = ldF(C_im, h*NN+n, flags[6]);
        CBt[(n*2+0)*HH + h] = cre*bre - cim*bim;
        CBt[(n*2+1)*HH + h] = cre*bim + cim*bre;
    }
    if (t < NN * 64) {          // V tables: lam_n^{tau+1}
        int n = t >> 6, tau = t & 63;
        float nu = expf(ldF(nu_log, n, flags[1]));
        float th = expf(ldF(theta_log, n, flags[2]));
        float p  = (float)(tau + 1);
        float ar = expf(-p * nu);
        Vre[n*64 + tau] = ar * cosf(p * th);
        Vim[n*64 + tau] = ar * sinf(p * th);
    }
}

// Conv taps: Ktab[j][h] = Re(sum_n CB[h,n] lam_n^j)
__global__ __launch_bounds__(256) void k_ktab(
    const float* __restrict__ CBt, const float* __restrict__ Vre,
    const float* __restrict__ Vim, float* __restrict__ Ktab)
{
    int t = blockIdx.x * 256 + threadIdx.x;   // 16384 threads
    int h = t >> 6, j = t & 63;
    float acc = 0.f;
    if (j == 0) {
        for (int n = 0; n < NN; ++n) acc += CBt[(2*n)*HH + h];
    } else {
        for (int n = 0; n < NN; ++n) {
            acc += CBt[(2*n)*HH + h]   * Vre[n*64 + (j-1)];
            acc -= CBt[(2*n+1)*HH + h] * Vim[n*64 + (j-1)];
        }
    }
    Ktab[j*HH + h] = acc;
}

// ---------- Phase A: A[s][n] = sum_l lam^(63-l) x_l (recurrence over xv) ----
template<bool ISBF>
__device__ __forceinline__ void segsum_body(
    const void* __restrict__ x, size_t xoff, const float* __restrict__ lam,
    __hip_bfloat16* __restrict__ Abuf, size_t abase, int n0)
{
    float xv[LSEG];
    #pragma unroll
    for (int l = 0; l < LSEG; ++l) {
        if (ISBF) xv[l] = __bfloat162float(((const __hip_bfloat16*)x)[xoff + (size_t)l*HH]);
        else      xv[l] = ((const float*)x)[xoff + (size_t)l*HH];
    }
    for (int n = n0; n < n0 + 32; ++n) {
        float lre = lam[2*n], lim = lam[2*n+1];
        float are = 0.f, aim = 0.f;
        #pragma unroll
        for (int l = 0; l < LSEG; ++l) {
            float t0 = lim * are;
            are = fmaf(lre, are, xv[l]);
            are = fmaf(-lim, aim, are);
            aim = fmaf(lre, aim, t0);
        }
        Abuf[abase + (size_t)n*128]      = __float2bfloat16(are);
        Abuf[abase + (size_t)n*128 + 64] = __float2bfloat16(aim);
    }
}

__global__ __launch_bounds__(256, 4) void k_segsum(
    const void* __restrict__ x, const float* __restrict__ lam,
    const int* __restrict__ flags, __hip_bfloat16* __restrict__ Abuf)
{
    int w    = blockIdx.x * 4 + (threadIdx.x >> 6);   // 0..4095
    int lane = threadIdx.x & 63;
    int half = w & 1;
    int seg  = (w >> 1) & (NSEG - 1);
    int hg   = (w >> 8) & 3;
    int b    = w >> 10;

    size_t xoff  = (size_t)(b*LL + seg*LSEG) * HH + hg*64 + lane;
    size_t abase = (((size_t)(b*4 + hg) * NSEG + seg) * NN) * 128 + lane;
    int n0 = half * 32;

    if (flags[0]) segsum_body<true >(x, xoff, lam, Abuf, abase, n0);
    else          segsum_body<false>(x, xoff, lam, Abuf, abase, n0);
}

// ---------- Phase B: scan + U epilogue (in place over Abuf) ----------
// Per step s: U[s] = CB * S_{s-1}  (store over A[s] after loading it),
//             S_s  = lam64 * S_{s-1} + A[s].
__global__ __launch_bounds__(256) void k_scan(
    const float* __restrict__ lam64, const float* __restrict__ CBt,
    __hip_bfloat16* __restrict__ Abuf)
{
    int w    = blockIdx.x * 4 + (threadIdx.x >> 6);
    int lane = threadIdx.x & 63;           // = h low bits
    int n    = w & 63;
    int hg   = (w >> 6) & 3;
    int b    = w >> 8;
    int h    = hg*64 + lane;

    float lre = lam64[2*n], lim = lam64[2*n+1];
    float cbre = CBt[(2*n)*HH + h], cbim = CBt[(2*n+1)*HH + h];
    float sre = 0.f, sim = 0.f;
    size_t base0 = (((size_t)(b*4 + hg) * NSEG) * NN + n) * 128 + lane;
    for (int s = 0; s < NSEG; ++s) {
        size_t base = base0 + (size_t)s * NN * 128;
        float are = __bfloat162float(Abuf[base]);
        float aim = __bfloat162float(Abuf[base + 64]);
        float ure = cbre*sre - cbim*sim;
        float uim = cbre*sim + cbim*sre;
        Abuf[base]      = __float2bfloat16(ure);
        Abuf[base + 64] = __float2bfloat16(uim);
        float t = fmaf(lre, sre, fmaf(-lim, sim, are));
        sim = fmaf(lre, sim, fmaf(lim, sre, aim));
        sre = t;
    }
}

// ---------- Phase C: y = D*x + local Toeplitz conv + carry matvec ----------
template<bool ISBF>
__device__ __forceinline__ void out_body(
    const void* __restrict__ x, int b, int s, int u, int h,
    const float* __restrict__ Df, const float* __restrict__ Ktab,
    const float* __restrict__ Vre, const float* __restrict__ Vim,
    const __hip_bfloat16* __restrict__ Up,   // &Abuf[(bg*128+s)*64*128 + lane]
    float* __restrict__ y)
{
    int row0 = s*LSEG + u*16;                 // first output row of this slice
    size_t rbase = ((size_t)b*LL + row0) * HH + h;

    float xv[16], yv[16];
    float dh = Df[h];
    #pragma unroll
    for (int t = 0; t < 16; ++t) {
        float xl;
        if (ISBF) xl = __bfloat162float(((const __hip_bfloat16*)x)[rbase + (size_t)t*HH]);
        else      xl = ((const float*)x)[rbase + (size_t)t*HH];
        xv[t] = xl;
        yv[t] = dh * xl;
    }

    // (a) taps j=0..15 against in-register xv (j<=t)
    #pragma unroll
    for (int j = 0; j < 16; ++j) {
        float kj = Ktab[j*HH + h];
        #pragma unroll
        for (int t = j; t < 16; ++t) yv[t] = fmaf(kj, xv[t-j], yv[t]);
    }

    // (b) taps j=t+1..16u+t against older x in this segment (u>0 only)
    int M = 16*u;
    for (int m = 0; m < M; ++m) {
        size_t ro = ((size_t)b*LL + (row0 - 1 - m)) * HH + h;
        float xm;
        if (ISBF) xm = __bfloat162float(((const __hip_bfloat16*)x)[ro]);
        else      xm = ((const float*)x)[ro];
        #pragma unroll
        for (int t = 0; t < 16; ++t)
            yv[t] = fmaf(Ktab[(t+1+m)*HH + h], xm, yv[t]);
    }

    // carry: yv[t] += sum_n Ure*Vre[n][16u+t] - Uim*Vim[n][16u+t]
    const float* vr0 = Vre + u*16;
    const float* vi0 = Vim + u*16;
    for (int n = 0; n < NN; ++n) {
        float ure = __bfloat162float(Up[(size_t)n*128]);
        float uim = __bfloat162float(Up[(size_t)n*128 + 64]);
        const float* vr = vr0 + n*64;
        const float* vi = vi0 + n*64;
        #pragma unroll
        for (int t = 0; t < 16; ++t) {
            yv[t] = fmaf(ure, vr[t], yv[t]);
            yv[t] = fmaf(-uim, vi[t], yv[t]);
        }
    }

    #pragma unroll
    for (int t = 0; t < 16; ++t) y[rbase + (size_t)t*HH] = yv[t];
}

__global__ __launch_bounds__(256, 4) void k_out(
    const void* __restrict__ x, const float* __restrict__ Df,
    const float* __restrict__ Ktab, const float* __restrict__ Vre,
    const float* __restrict__ Vim, const int* __restrict__ flags,
    const __hip_bfloat16* __restrict__ Abuf, float* __restrict__ y)
{
    int bk   = blockIdx.x;              // 0..2047
    int u    = bk & 3;
    int s    = (bk >> 2) & (NSEG - 1);
    int b    = bk >> 9;
    int hg   = threadIdx.x >> 6;
    int lane = threadIdx.x & 63;
    int h    = hg*64 + lane;

    const __hip_bfloat16* Up =
        Abuf + (((size_t)(b*4 + hg) * NSEG + s) * NN) * 128 + lane;

    if (flags[0]) out_body<true >(x, b, s, u, h, Df, Ktab, Vre, Vim, Up, y);
    else          out_body<false>(x, b, s, u, h, Df, Ktab, Vre, Vim, Up, y);
}

extern "C" void kernel_launch(void* const* d_in, const int* in_sizes, int n_in,
                              void* d_out, int out_size, void* d_ws, size_t ws_size,
                              hipStream_t stream)
{
    const void* x  = d_in[0];
    const void* nu = d_in[1];
    const void* th = d_in[2];
    const void* Br = d_in[3];
    const void* Bi = d_in[4];
    const void* Cr = d_in[5];
    const void* Ci = d_in[6];
    const void* D  = d_in[7];

    char* ws = (char*)d_ws;
    float* lam   = (float*)(ws);
    float* lam64 = (float*)(ws + 512);
    int*   flags = (int*)(ws + 1024);
    float* Df    = (float*)(ws + 1088);
    float* CBt   = (float*)(ws + 2112);
    float* Ktab  = (float*)(ws + 133184);
    float* Vre   = (float*)(ws + 198720);
    float* Vim   = (float*)(ws + 215104);
    __hip_bfloat16* Abuf = (__hip_bfloat16*)(ws + 262144);
    float* yout = (float*)d_out;

    k_sniff<<<dim3(1), dim3(64), 0, stream>>>(x, nu, th, Br, Bi, Cr, Ci, D, flags);
    k_setup<<<dim3(64), dim3(256), 0, stream>>>(nu, th, Br, Bi, Cr, Ci, D, flags,
                                                lam, lam64, Df, CBt, Vre, Vim);
    k_ktab<<<dim3(64), dim3(256), 0, stream>>>(CBt, Vre, Vim, Ktab);
    k_segsum<<<dim3(1024), dim3(256), 0, stream>>>(x, lam, flags, Abuf);
    k_scan<<<dim3(256), dim3(256), 0, stream>>>(lam64, CBt, Abuf);
    k_out<<<dim3(2048), dim3(256), 0, stream>>>(x, Df, Ktab, Vre, Vim, flags,
                                                Abuf, yout);
}

// Round 7
// 230.130 us; speedup vs baseline: 1.1763x; 1.1763x over previous
//
#include <hip/hip_runtime.h>
#include <hip/hip_bf16.h>

#define BB   4
#define LL   8192
#define HH   256
#define NN   64
#define NSEG 128
#define LSEG 64

typedef __attribute__((ext_vector_type(8))) short  short8;
typedef __attribute__((ext_vector_type(4))) float  float4v;
typedef __attribute__((ext_vector_type(4))) int    int4v;

// ws layout (bytes):
//       0 : lam[128]     f32   lambda (re,im)
//     512 : lam64[128]   f32   lambda^64
//    1024 : flags[8]     i32
//    1088 : Df[256]      f32
//    2112 : CBt[128*256] f32   [n2][h]
//  133184 : Ktab[64*256] f32   [j][h]   K[h,j]=Re(sum_n CB lam^j)
//  198720 : VreT[64*64]  bf16  [tau][n] Re(lam^{tau+1})        (MFMA A-layout)
//  206912 : VimnT[64*64] bf16  [tau][n] -Im(lam^{tau+1})
//  215104 : PtabRe[64*65]f32   [n][p]   Re(lam^p) exact
//  231744 : PtabIm[64*65]f32
//  262144 : Abuf bf16 33 MB    [b*4+hg][s][n][reim][64 lane-h]  A ->(scan)-> U
//
// R7: carry term = GEMM  Yc(64tau x 256h) = VreT·Ure + (-VimT)·Uim  per (b,s)
// via mfma_f32_16x16x32_bf16, written fp32 straight into d_out; k_conv then
// does y += D*x + segment-local triangular conv (x staged in LDS).

__device__ __forceinline__ float ldF(const void* p, size_t i, int isbf) {
    return isbf ? __bfloat162float(((const __hip_bfloat16*)p)[i])
                : ((const float*)p)[i];
}

__global__ void k_sniff(const void* p0, const void* p1, const void* p2,
                        const void* p3, const void* p4, const void* p5,
                        const void* p6, const void* p7, int* flags)
{
    int t = threadIdx.x;
    if (t < 8) {
        const void* ps[8] = {p0, p1, p2, p3, p4, p5, p6, p7};
        const unsigned int* d = (const unsigned int*)ps[t];
        int nbf = 0, nrand = 0;
        for (int i = 0; i < 32; ++i) {
            unsigned int lo = d[i] & 0xFFFFu;
            unsigned int e  = (lo >> 7) & 0xFFu;
            if (lo == 0u) { /* neutral */ }
            else if (e >= 90u && e <= 140u) nbf++;
            else nrand++;
        }
        flags[t] = (nrand == 0 && nbf >= 8) ? 1 : 0;
    }
}

__global__ __launch_bounds__(256) void k_setup(
    const void* nu_log, const void* theta_log,
    const void* B_re, const void* B_im,
    const void* C_re, const void* C_im,
    const void* D, const int* __restrict__ flags,
    float* lam, float* lam64, float* Df, float* CBt,
    float* PtabRe, float* PtabIm)
{
    int t = blockIdx.x * 256 + threadIdx.x;
    if (t < NN) {
        float nu = expf(ldF(nu_log, t, flags[1]));
        float th = expf(ldF(theta_log, t, flags[2]));
        float a  = expf(-nu);
        lam[2*t]   = a * cosf(th);
        lam[2*t+1] = a * sinf(th);
        float a64 = expf(-64.0f * nu);
        float ph  = 64.0f * th;
        lam64[2*t]   = a64 * cosf(ph);
        lam64[2*t+1] = a64 * sinf(ph);
    }
    if (t < HH) Df[t] = ldF(D, t, flags[7]);
    if (t < HH * NN) {
        int h = t >> 6, n = t & 63;
        float bre = ldF(B_re, h*NN+n, flags[3]);
        float bim = ldF(B_im, h*NN+n, flags[4]);
        float cre = ldF(C_re, h*NN+n, flags[5]);
        float cim = ldF(C_im, h*NN+n, flags[6]);
        CBt[(n*2+0)*HH + h] = cre*bre - cim*bim;
        CBt[(n*2+1)*HH + h] = cre*bim + cim*bre;
    }
    if (t < NN * 65) {
        int n = t / 65, p = t - n*65;
        float nu = expf(ldF(nu_log, n, flags[1]));
        float th = expf(ldF(theta_log, n, flags[2]));
        float fp = (float)p;
        float ar = expf(-fp * nu);
        PtabRe[t] = ar * cosf(fp * th);
        PtabIm[t] = ar * sinf(fp * th);
    }
}

// Ktab from exact f32 powers; V tables (bf16, [tau][n]) for the carry GEMM.
__global__ __launch_bounds__(256) void k_ktab(
    const float* __restrict__ CBt, const float* __restrict__ PtabRe,
    const float* __restrict__ PtabIm, float* __restrict__ Ktab,
    short* __restrict__ VreT, short* __restrict__ VimnT)
{
    int t = blockIdx.x * 256 + threadIdx.x;    // 16384
    int h = t >> 6, j = t & 63;
    float acc = 0.f;
    for (int n = 0; n < NN; ++n)
        acc += CBt[(2*n)*HH + h]   * PtabRe[n*65 + j]
             - CBt[(2*n+1)*HH + h] * PtabIm[n*65 + j];
    Ktab[j*HH + h] = acc;
    if (t < 64*64) {
        int tau = t >> 6, n = t & 63;
        __hip_bfloat16 vr = __float2bfloat16(PtabRe[n*65 + tau + 1]);
        __hip_bfloat16 vi = __float2bfloat16(-PtabIm[n*65 + tau + 1]);
        VreT[tau*64 + n]  = *(short*)&vr;
        VimnT[tau*64 + n] = *(short*)&vi;
    }
}

// ---------- Phase A: A[s][n] = sum_l lam^(63-l) x_l ----------
template<bool ISBF>
__device__ __forceinline__ void segsum_body(
    const void* __restrict__ x, size_t xoff, const float* __restrict__ lam,
    __hip_bfloat16* __restrict__ Abuf, size_t abase, int n0)
{
    float xv[LSEG];
    #pragma unroll
    for (int l = 0; l < LSEG; ++l) {
        if (ISBF) xv[l] = __bfloat162float(((const __hip_bfloat16*)x)[xoff + (size_t)l*HH]);
        else      xv[l] = ((const float*)x)[xoff + (size_t)l*HH];
    }
    for (int n = n0; n < n0 + 32; ++n) {
        float lre = lam[2*n], lim = lam[2*n+1];
        float are = 0.f, aim = 0.f;
        #pragma unroll
        for (int l = 0; l < LSEG; ++l) {
            float t0 = lim * are;
            are = fmaf(lre, are, xv[l]);
            are = fmaf(-lim, aim, are);
            aim = fmaf(lre, aim, t0);
        }
        Abuf[abase + (size_t)n*128]      = __float2bfloat16(are);
        Abuf[abase + (size_t)n*128 + 64] = __float2bfloat16(aim);
    }
}

__global__ __launch_bounds__(256, 4) void k_segsum(
    const void* __restrict__ x, const float* __restrict__ lam,
    const int* __restrict__ flags, __hip_bfloat16* __restrict__ Abuf)
{
    int w    = blockIdx.x * 4 + (threadIdx.x >> 6);
    int lane = threadIdx.x & 63;
    int half = w & 1;
    int seg  = (w >> 1) & (NSEG - 1);
    int hg   = (w >> 8) & 3;
    int b    = w >> 10;

    size_t xoff  = (size_t)(b*LL + seg*LSEG) * HH + hg*64 + lane;
    size_t abase = (((size_t)(b*4 + hg) * NSEG + seg) * NN) * 128 + lane;
    int n0 = half * 32;

    if (flags[0]) segsum_body<true >(x, xoff, lam, Abuf, abase, n0);
    else          segsum_body<false>(x, xoff, lam, Abuf, abase, n0);
}

// ---------- Phase B: scan + U = CB*S_{s-1} epilogue (in place) ----------
__global__ __launch_bounds__(256) void k_scan(
    const float* __restrict__ lam64, const float* __restrict__ CBt,
    __hip_bfloat16* __restrict__ Abuf)
{
    int w    = blockIdx.x * 4 + (threadIdx.x >> 6);
    int lane = threadIdx.x & 63;
    int n    = w & 63;
    int hg   = (w >> 6) & 3;
    int b    = w >> 8;
    int h    = hg*64 + lane;

    float lre = lam64[2*n], lim = lam64[2*n+1];
    float cbre = CBt[(2*n)*HH + h], cbim = CBt[(2*n+1)*HH + h];
    float sre = 0.f, sim = 0.f;
    size_t base0 = (((size_t)(b*4 + hg) * NSEG) * NN + n) * 128 + lane;
    for (int s = 0; s < NSEG; ++s) {
        size_t base = base0 + (size_t)s * NN * 128;
        float are = __bfloat162float(Abuf[base]);
        float aim = __bfloat162float(Abuf[base + 64]);
        float ure = cbre*sre - cbim*sim;
        float uim = cbre*sim + cbim*sre;
        Abuf[base]      = __float2bfloat16(ure);
        Abuf[base + 64] = __float2bfloat16(uim);
        float t = fmaf(lre, sre, fmaf(-lim, sim, are));
        sim = fmaf(lre, sim, fmaf(lim, sre, aim));
        sre = t;
    }
}

// ---------- Phase C1: carry GEMM via MFMA, writes fp32 into d_out ----------
// Yc[tau,h] = sum_n VreT[tau,n]*Ure[n,h] + (-VimT[tau,n])*Uim[n,h]
__global__ __launch_bounds__(256) void k_carry(
    const short* __restrict__ VreT, const short* __restrict__ VimnT,
    const short* __restrict__ U, float* __restrict__ y)
{
    int bk = blockIdx.x;                 // 512 = (b, s)
    int s  = bk & (NSEG - 1);
    int b  = bk >> 7;
    int w    = threadIdx.x >> 6;         // wave = hg (64-h group)
    int lane = threadIdx.x & 63;
    int q = lane >> 4, l15 = lane & 15;
    size_t ubase = (((size_t)(b*4 + w) * NSEG + s) * NN) * 128;

    // A-frags: a[j] = A[m = l15 + 16*mt][k = q*8 + ks*32 + j], table [tau][n]
    short8 afr[4][2], afi[4][2];
    #pragma unroll
    for (int mt = 0; mt < 4; ++mt)
        #pragma unroll
        for (int ks = 0; ks < 2; ++ks) {
            int off = (mt*16 + l15)*64 + ks*32 + q*8;
            afr[mt][ks] = *(const short8*)(VreT + off);
            afi[mt][ks] = *(const short8*)(VimnT + off);
        }

    #pragma unroll
    for (int nt = 0; nt < 4; ++nt) {
        int l = nt*16 + l15;
        // B-frags: b[j] = B[k = n][col = h], U layout [n][reim][64 lane-h]
        short8 bre[2], bim[2];
        #pragma unroll
        for (int ks = 0; ks < 2; ++ks)
            #pragma unroll
            for (int j = 0; j < 8; ++j) {
                int n = ks*32 + q*8 + j;
                bre[ks][j] = U[ubase + (size_t)n*128 + l];
                bim[ks][j] = U[ubase + (size_t)n*128 + 64 + l];
            }
        int h = w*64 + l;
        #pragma unroll
        for (int mt = 0; mt < 4; ++mt) {
            float4v acc = {0.f, 0.f, 0.f, 0.f};
            #pragma unroll
            for (int ks = 0; ks < 2; ++ks) {
                acc = __builtin_amdgcn_mfma_f32_16x16x32_bf16(afr[mt][ks], bre[ks], acc, 0, 0, 0);
                acc = __builtin_amdgcn_mfma_f32_16x16x32_bf16(afi[mt][ks], bim[ks], acc, 0, 0, 0);
            }
            // D: col = l15 (h), row = q*4 + r (tau)
            #pragma unroll
            for (int r = 0; r < 4; ++r) {
                int tau = mt*16 + q*4 + r;
                y[((size_t)b*LL + s*64 + tau)*HH + h] = acc[r];
            }
        }
    }
}

// ---------- Phase C2: y += D*x + segment-local triangular conv ----------
template<bool ISBF, int U>
__device__ __forceinline__ void conv_u(
    const void* __restrict__ x, const float* __restrict__ Df,
    const float* __restrict__ Ktab, const short* __restrict__ xs,
    int b, int s, int h, float* __restrict__ y)
{
    int g0 = s*64 + U*16;
    size_t rbase = ((size_t)b*LL + g0)*HH + h;
    float xv[16], yv[16];
    float dh = Df[h];
    #pragma unroll
    for (int t = 0; t < 16; ++t) {
        float xl;
        if (ISBF) xl = __bfloat162float(((const __hip_bfloat16*)x)[rbase + (size_t)t*HH]);
        else      xl = ((const float*)x)[rbase + (size_t)t*HH];
        xv[t] = xl;
        yv[t] = fmaf(dh, xl, y[rbase + (size_t)t*HH]);   // carry already in y
    }
    float kreg[16*U + 16];
    #pragma unroll
    for (int j = 0; j < 16*U + 16; ++j) kreg[j] = Ktab[j*HH + h];
    // taps j=0..15 vs in-register xv (j<=t)
    #pragma unroll
    for (int j = 0; j < 16; ++j)
        #pragma unroll
        for (int t = j; t < 16; ++t) yv[t] = fmaf(kreg[j], xv[t-j], yv[t]);
    // taps j=t+1..16U+t vs older rows from LDS
    #pragma unroll
    for (int m = 0; m < 16*U; ++m) {
        short bits = xs[(U*16 - 1 - m)*HH + h];
        float xm = __bfloat162float(*(const __hip_bfloat16*)&bits);
        #pragma unroll
        for (int t = 0; t < 16; ++t) yv[t] = fmaf(kreg[t+1+m], xm, yv[t]);
    }
    #pragma unroll
    for (int t = 0; t < 16; ++t) y[rbase + (size_t)t*HH] = yv[t];
}

template<bool ISBF>
__device__ __forceinline__ void conv_block(
    const void* __restrict__ x, const float* __restrict__ Df,
    const float* __restrict__ Ktab, short* xs, int b, int s,
    float* __restrict__ y)
{
    int t = threadIdx.x;
    size_t sb = ((size_t)b*LL + s*64) * HH;
    if (ISBF) {
        const int4v* xp = (const int4v*)((const __hip_bfloat16*)x + sb);
        int4v* xd = (int4v*)xs;
        xd[t]        = xp[t];
        xd[t + 1024] = xp[t + 1024];
    } else {
        const float* xp = (const float*)x + sb;
        #pragma unroll
        for (int i = 0; i < 2; ++i) {
            int e = (t + i*1024) * 8;
            #pragma unroll
            for (int j = 0; j < 8; ++j) {
                __hip_bfloat16 v = __float2bfloat16(xp[e + j]);
                xs[e + j] = *(short*)&v;
            }
        }
    }
    __syncthreads();
    int w = t >> 6, lane = t & 63;
    int u = w >> 2, hg = w & 3;
    int h = hg*64 + lane;
    switch (u) {
        case 0: conv_u<ISBF,0>(x, Df, Ktab, xs, b, s, h, y); break;
        case 1: conv_u<ISBF,1>(x, Df, Ktab, xs, b, s, h, y); break;
        case 2: conv_u<ISBF,2>(x, Df, Ktab, xs, b, s, h, y); break;
        case 3: conv_u<ISBF,3>(x, Df, Ktab, xs, b, s, h, y); break;
    }
}

__global__ __launch_bounds__(1024) void k_conv(
    const void* __restrict__ x, const float* __restrict__ Df,
    const float* __restrict__ Ktab, const int* __restrict__ flags,
    float* __restrict__ y)
{
    __shared__ short xs[64 * HH];
    int bk = blockIdx.x;
    int s  = bk & (NSEG - 1);
    int b  = bk >> 7;
    if (flags[0]) conv_block<true >(x, Df, Ktab, xs, b, s, y);
    else          conv_block<false>(x, Df, Ktab, xs, b, s, y);
}

extern "C" void kernel_launch(void* const* d_in, const int* in_sizes, int n_in,
                              void* d_out, int out_size, void* d_ws, size_t ws_size,
                              hipStream_t stream)
{
    const void* x  = d_in[0];
    const void* nu = d_in[1];
    const void* th = d_in[2];
    const void* Br = d_in[3];
    const void* Bi = d_in[4];
    const void* Cr = d_in[5];
    const void* Ci = d_in[6];
    const void* D  = d_in[7];

    char* ws = (char*)d_ws;
    float* lam    = (float*)(ws);
    float* lam64  = (float*)(ws + 512);
    int*   flags  = (int*)(ws + 1024);
    float* Df     = (float*)(ws + 1088);
    float* CBt    = (float*)(ws + 2112);
    float* Ktab   = (float*)(ws + 133184);
    short* VreT   = (short*)(ws + 198720);
    short* VimnT  = (short*)(ws + 206912);
    float* PtabRe = (float*)(ws + 215104);
    float* PtabIm = (float*)(ws + 231744);
    __hip_bfloat16* Abuf = (__hip_bfloat16*)(ws + 262144);
    float* yout = (float*)d_out;

    k_sniff<<<dim3(1), dim3(64), 0, stream>>>(x, nu, th, Br, Bi, Cr, Ci, D, flags);
    k_setup<<<dim3(64), dim3(256), 0, stream>>>(nu, th, Br, Bi, Cr, Ci, D, flags,
                                                lam, lam64, Df, CBt, PtabRe, PtabIm);
    k_ktab<<<dim3(64), dim3(256), 0, stream>>>(CBt, PtabRe, PtabIm, Ktab, VreT, VimnT);
    k_segsum<<<dim3(1024), dim3(256), 0, stream>>>(x, lam, flags, Abuf);
    k_scan<<<dim3(256), dim3(256), 0, stream>>>(lam64, CBt, Abuf);
    k_carry<<<dim3(512), dim3(256), 0, stream>>>(VreT, VimnT, (const short*)Abuf, yout);
    k_conv<<<dim3(512), dim3(1024), 0, stream>>>(x, Df, Ktab, flags, yout);
}